// Round 1
// baseline (484.739 us; speedup 1.0000x reference)
//
#include <hip/hip_runtime.h>
#include <math.h>

#define BATCH 1024
#define NU 1000
#define NI 1000
#define EDIM 128
#define INROW 66    // 2 + UF + IF
#define IN_SIZE 320 // E + UF + E + IF
#define OUTROW 258  // 2 + 2*E
#define G 4         // batch rows per compute block

// ---------------------------------------------------------------------------
// Compute kernel: per block handles G=4 batch rows.
//   gi = x @ w_ih^T   (768 rows total: 384 user + 384 item)
//   gates + L2 normalize, write out rows [uid, iid, new_u(128), new_i(128)]
// ---------------------------------------------------------------------------
__global__ __launch_bounds__(256) void limnet_compute(
    const float* __restrict__ inputs,
    const float* __restrict__ umem,
    const float* __restrict__ imem,
    const float* __restrict__ w_u, const float* __restrict__ bih_u, const float* __restrict__ bhh_u,
    const float* __restrict__ w_i, const float* __restrict__ bih_i, const float* __restrict__ bhh_i,
    float* __restrict__ out)
{
    __shared__ float xx[G][640];   // x_u duplicated: x_i[k] == xx[160+k]
    __shared__ float gi[G][768];   // 384 user rows then 384 item rows
    __shared__ float psum[4][G];
    __shared__ int   ids[G][2];

    const int t = threadIdx.x;
    const int wave = t >> 6, lane = t & 63;
    const int b0 = blockIdx.x * G;

    // ---- stage x vectors ----
    for (int g = 0; g < G; ++g) {
        const int b = b0 + g;
        const float* inrow = inputs + (long)b * INROW;
        const int uid = (int)inrow[0];
        const int iid = (int)inrow[1];
        if (t == 0) { ids[g][0] = uid; ids[g][1] = iid; }
        if (t < 128) {
            float v = umem[((long)b * NU + uid) * EDIM + t];
            xx[g][t]       = v;  xx[g][320 + t] = v;
            float w = imem[((long)b * NI + iid) * EDIM + t];
            xx[g][160 + t] = w;  xx[g][480 + t] = w;
        } else {
            int s = t - 128;
            if (s < 32)      { float v = inrow[2 + s];  xx[g][128 + s] = v; xx[g][448 + s] = v; }
            else if (s < 64) { int s2 = s - 32; float v = inrow[34 + s2]; xx[g][288 + s2] = v; xx[g][608 + s2] = v; }
        }
    }
    __syncthreads();

    // ---- GEMM: each wave owns 192 contiguous rows (waves 0,1: user; 2,3: item) ----
    const int r0 = wave * 192;
    for (int rr = 0; rr < 192; ++rr) {
        const int row = r0 + rr;                    // wave-uniform branch below
        const float* wrow;
        int xoff;
        if (row < 384) { wrow = w_u + (long)row * IN_SIZE;          xoff = 0;   }
        else           { wrow = w_i + (long)(row - 384) * IN_SIZE;  xoff = 160; }

        float wv[5];
        #pragma unroll
        for (int k5 = 0; k5 < 5; ++k5) wv[k5] = wrow[lane + 64 * k5];   // coalesced

        float p[G];
        #pragma unroll
        for (int g = 0; g < G; ++g) {
            float acc = 0.f;
            #pragma unroll
            for (int k5 = 0; k5 < 5; ++k5)
                acc += wv[k5] * xx[g][xoff + lane + 64 * k5];
            p[g] = acc;
        }
        #pragma unroll
        for (int off = 32; off >= 1; off >>= 1) {
            #pragma unroll
            for (int g = 0; g < G; ++g) p[g] += __shfl_xor(p[g], off);
        }
        if (lane == 0) {
            #pragma unroll
            for (int g = 0; g < G; ++g) gi[g][row] = p[g];
        }
    }
    __syncthreads();

    // ---- gates + L2 norm: t<128 -> user dim d=t ; t>=128 -> item dim d=t-128 ----
    const int isItem = (t >= 128);
    const int d = isItem ? (t - 128) : t;
    const float* bih = isItem ? bih_i : bih_u;
    const float* bhh = isItem ? bhh_i : bhh_u;
    const float br = bih[d]       + bhh[d];
    const float bz = bih[128 + d] + bhh[128 + d];
    const float bn = bih[256 + d];
    const float hn = bhh[256 + d];
    const int gibase = isItem ? 384 : 0;

    float val[G], ss[G];
    #pragma unroll
    for (int g = 0; g < G; ++g) {
        float ir  = gi[g][gibase + d];
        float iz  = gi[g][gibase + 128 + d];
        float inn = gi[g][gibase + 256 + d];
        float r = 1.f / (1.f + expf(-(ir + br)));
        float z = 1.f / (1.f + expf(-(iz + bz)));
        float n = tanhf(inn + bn + r * hn);
        val[g] = (1.f - z) * n;
        ss[g]  = val[g] * val[g];
    }
    #pragma unroll
    for (int off = 32; off >= 1; off >>= 1) {
        #pragma unroll
        for (int g = 0; g < G; ++g) ss[g] += __shfl_xor(ss[g], off);
    }
    if (lane == 0) {
        #pragma unroll
        for (int g = 0; g < G; ++g) psum[wave][g] = ss[g];
    }
    __syncthreads();

    #pragma unroll
    for (int g = 0; g < G; ++g) {
        float s = isItem ? (psum[2][g] + psum[3][g]) : (psum[0][g] + psum[1][g]);
        float denom = fmaxf(sqrtf(s), 1e-12f);
        float nv = val[g] / denom;
        out[(long)(b0 + g) * OUTROW + 2 + (isItem ? 128 : 0) + d] = nv;
    }
    if (t < 2 * G) {
        int g = t >> 1, col = t & 1;
        out[(long)(b0 + g) * OUTROW + col] = (float)ids[g][col];
    }
}

// ---------------------------------------------------------------------------
// Copy kernel: full memory array -> d_out section, replacing each batch row's
// updated id-row with the freshly computed normalized vector (read from the
// out section written by limnet_compute earlier on the same stream).
// Half-wave (32 lanes x float4) per 128-float row; 8 rows per 256-thread block.
// ---------------------------------------------------------------------------
__global__ __launch_bounds__(256) void limnet_copy(
    const float* __restrict__ mem,
    const float* __restrict__ inputs,
    const float* __restrict__ outbase,   // d_out (out section, for new values)
    float* __restrict__ dst,             // d_out + section offset
    int idcol, int newcol)
{
    const int row = blockIdx.x * 8 + (threadIdx.x >> 5);
    const int l   = threadIdx.x & 31;
    const int b   = row / 1000;          // compile-time magic div
    const int n   = row - b * 1000;
    const int id  = (int)inputs[b * INROW + idcol];
    const long off = (long)row * EDIM + l * 4;
    float4 v;
    if (n == id) {
        const float* nr = outbase + (long)b * OUTROW + newcol;  // not 16B aligned -> scalar
        v = make_float4(nr[l * 4], nr[l * 4 + 1], nr[l * 4 + 2], nr[l * 4 + 3]);
    } else {
        v = *(const float4*)(mem + off);
    }
    *(float4*)(dst + off) = v;
}

extern "C" void kernel_launch(void* const* d_in, const int* in_sizes, int n_in,
                              void* d_out, int out_size, void* d_ws, size_t ws_size,
                              hipStream_t stream) {
    const float* inputs = (const float*)d_in[0];
    const float* umem   = (const float*)d_in[1];
    const float* imem   = (const float*)d_in[2];
    const float* w_u    = (const float*)d_in[3];
    const float* bih_u  = (const float*)d_in[4];
    const float* bhh_u  = (const float*)d_in[5];
    const float* w_i    = (const float*)d_in[6];
    const float* bih_i  = (const float*)d_in[7];
    const float* bhh_i  = (const float*)d_in[8];
    float* out = (float*)d_out;

    limnet_compute<<<BATCH / G, 256, 0, stream>>>(
        inputs, umem, imem, w_u, bih_u, bhh_u, w_i, bih_i, bhh_i, out);

    const long OUTSEC = (long)BATCH * OUTROW;       // 264192
    const long MEMSZ  = (long)BATCH * NU * EDIM;    // 131072000

    limnet_copy<<<(BATCH * NU) / 8, 256, 0, stream>>>(
        umem, inputs, out, out + OUTSEC, 0, 2);
    limnet_copy<<<(BATCH * NI) / 8, 256, 0, stream>>>(
        imem, inputs, out, out + OUTSEC + MEMSZ, 1, 130);
}

// Round 3
// 436.577 us; speedup vs baseline: 1.1103x; 1.1103x over previous
//
#include <hip/hip_runtime.h>
#include <math.h>

#define BATCH 1024
#define NU 1000
#define NI 1000
#define EDIM 128
#define INROW 66    // 2 + UF + IF
#define IN_SIZE 320 // E + UF + E + IF
#define OUTROW 258  // 2 + 2*E
#define G 4         // batch rows per compute block
#define CHUNKS 5    // copy blocks per batch row (32000 float4 / 5 = 6400)

typedef float f32x4 __attribute__((ext_vector_type(4)));

// ---------------------------------------------------------------------------
// Compute kernel: per block handles G=4 batch rows.
//   gi = x @ w_ih^T   (768 rows total: 384 user + 384 item)
//   16 lanes per row, x fragments hoisted to registers, float4 weight loads.
// ---------------------------------------------------------------------------
__global__ __launch_bounds__(256) void limnet_compute(
    const float* __restrict__ inputs,
    const float* __restrict__ umem,
    const float* __restrict__ imem,
    const float* __restrict__ w_u, const float* __restrict__ bih_u, const float* __restrict__ bhh_u,
    const float* __restrict__ w_i, const float* __restrict__ bih_i, const float* __restrict__ bhh_i,
    float* __restrict__ out)
{
    __shared__ float xx[G][640];   // x_u duplicated: x_i[k] == xx[160+k]
    __shared__ float gi[G][768];   // 384 user rows then 384 item rows
    __shared__ float psum[4][G];
    __shared__ int   ids[G][2];

    const int t = threadIdx.x;
    const int wave = t >> 6, lane = t & 63;
    const int lane16 = lane & 15, sub = lane >> 4;
    const int b0 = blockIdx.x * G;

    // ---- stage x vectors ----
    for (int g = 0; g < G; ++g) {
        const int b = b0 + g;
        const float* inrow = inputs + (long)b * INROW;
        const int uid = (int)inrow[0];
        const int iid = (int)inrow[1];
        if (t == 0) { ids[g][0] = uid; ids[g][1] = iid; }
        if (t < 128) {
            float v = umem[((long)b * NU + uid) * EDIM + t];
            xx[g][t]       = v;  xx[g][320 + t] = v;
            float w = imem[((long)b * NI + iid) * EDIM + t];
            xx[g][160 + t] = w;  xx[g][480 + t] = w;
        } else {
            int s = t - 128;
            if (s < 32)      { float v = inrow[2 + s];  xx[g][128 + s] = v; xx[g][448 + s] = v; }
            else if (s < 64) { int s2 = s - 32; float v = inrow[34 + s2]; xx[g][288 + s2] = v; xx[g][608 + s2] = v; }
        }
    }
    __syncthreads();

    // ---- hoist x fragments into registers (wave-uniform xoff) ----
    const int isItemW = (wave >= 2);
    const int xoff = isItemW ? 160 : 0;          // 640B -> float4-aligned
    f32x4 xv[G][5];
    #pragma unroll
    for (int g = 0; g < G; ++g)
        #pragma unroll
        for (int i = 0; i < 5; ++i)
            xv[g][i] = *(const f32x4*)&xx[g][xoff + lane16 * 4 + i * 64];

    // ---- GEMM: 16 lanes per row, 4 rows in flight per wave ----
    const float* wbase = isItemW ? w_i : w_u;
    const int rbase = (wave & 1) * 192;
    const int gibase = isItemW ? 384 : 0;
    for (int it = 0; it < 48; ++it) {
        const int row = rbase + it * 4 + sub;
        const float* wrow = wbase + (long)row * IN_SIZE;
        float acc[G] = {0.f, 0.f, 0.f, 0.f};
        #pragma unroll
        for (int i = 0; i < 5; ++i) {
            const f32x4 wv = *(const f32x4*)&wrow[lane16 * 4 + i * 64];
            #pragma unroll
            for (int g = 0; g < G; ++g)
                acc[g] += wv.x * xv[g][i].x + wv.y * xv[g][i].y
                        + wv.z * xv[g][i].z + wv.w * xv[g][i].w;
        }
        #pragma unroll
        for (int off = 8; off >= 1; off >>= 1) {
            #pragma unroll
            for (int g = 0; g < G; ++g) acc[g] += __shfl_xor(acc[g], off);
        }
        if (lane16 == 0) {
            #pragma unroll
            for (int g = 0; g < G; ++g) gi[g][gibase + row] = acc[g];
        }
    }
    __syncthreads();

    // ---- gates + L2 norm: t<128 -> user dim d=t ; t>=128 -> item dim d=t-128 ----
    const int isItem = (t >= 128);
    const int d = isItem ? (t - 128) : t;
    const float* bih = isItem ? bih_i : bih_u;
    const float* bhh = isItem ? bhh_i : bhh_u;
    const float br = bih[d]       + bhh[d];
    const float bz = bih[128 + d] + bhh[128 + d];
    const float bn = bih[256 + d];
    const float hn = bhh[256 + d];
    const int gib = isItem ? 384 : 0;

    float val[G], ss[G];
    #pragma unroll
    for (int g = 0; g < G; ++g) {
        float ir  = gi[g][gib + d];
        float iz  = gi[g][gib + 128 + d];
        float inn = gi[g][gib + 256 + d];
        float r = 1.f / (1.f + expf(-(ir + br)));
        float z = 1.f / (1.f + expf(-(iz + bz)));
        float n = tanhf(inn + bn + r * hn);
        val[g] = (1.f - z) * n;
        ss[g]  = val[g] * val[g];
    }
    #pragma unroll
    for (int off = 32; off >= 1; off >>= 1) {
        #pragma unroll
        for (int g = 0; g < G; ++g) ss[g] += __shfl_xor(ss[g], off);
    }
    if (lane == 0) {
        #pragma unroll
        for (int g = 0; g < G; ++g) psum[wave][g] = ss[g];
    }
    __syncthreads();

    #pragma unroll
    for (int g = 0; g < G; ++g) {
        float s = isItem ? (psum[2][g] + psum[3][g]) : (psum[0][g] + psum[1][g]);
        float denom = fmaxf(sqrtf(s), 1e-12f);
        float nv = val[g] / denom;
        out[(long)(b0 + g) * OUTROW + 2 + (isItem ? 128 : 0) + d] = nv;
    }
    if (t < 2 * G) {
        int g = t >> 1, col = t & 1;
        out[(long)(b0 + g) * OUTROW + col] = (float)ids[g][col];
    }
}

// ---------------------------------------------------------------------------
// Merged copy kernel: grid (BATCH*CHUNKS, 2). Each block copies a contiguous
// 6400-float4 chunk of one batch row's memory slab (user or item per grid.y),
// substituting the updated id-row from the out section. 25 deep float4
// iterations per thread, nontemporal bulk load/store, id loaded once/block.
// ---------------------------------------------------------------------------
__global__ __launch_bounds__(256) void limnet_copy(
    const float* __restrict__ umem,
    const float* __restrict__ imem,
    const float* __restrict__ inputs,
    const float* __restrict__ outbase,   // d_out (out section, for new values)
    float* __restrict__ udst,
    float* __restrict__ idst)
{
    const int item = blockIdx.y;
    const int b = blockIdx.x / CHUNKS;
    const int c = blockIdx.x - b * CHUNKS;
    const int t = threadIdx.x;

    const f32x4* __restrict__ src4 = (const f32x4*)(item ? imem : umem);
    f32x4* __restrict__ dst4 = (f32x4*)(item ? idst : udst);
    const int id = (int)inputs[(long)b * INROW + item];
    const float* __restrict__ newrow = outbase + (long)b * OUTROW + 2 + item * EDIM;

    const long bbase4 = (long)b * (NU * EDIM / 4);   // 32000 float4 per b
    const int  cbase4 = c * 6400;

    #pragma unroll 5
    for (int i = 0; i < 25; ++i) {
        const int idx4 = cbase4 + i * 256 + t;       // float4 index within b's slab
        const long g4 = bbase4 + idx4;
        f32x4 v = __builtin_nontemporal_load(&src4[g4]);
        if ((idx4 >> 5) == id) {                     // row being replaced
            const int o = (idx4 & 31) * 4;
            f32x4 nv = { newrow[o], newrow[o + 1], newrow[o + 2], newrow[o + 3] };
            v = nv;
        }
        __builtin_nontemporal_store(v, &dst4[g4]);
    }
}

extern "C" void kernel_launch(void* const* d_in, const int* in_sizes, int n_in,
                              void* d_out, int out_size, void* d_ws, size_t ws_size,
                              hipStream_t stream) {
    const float* inputs = (const float*)d_in[0];
    const float* umem   = (const float*)d_in[1];
    const float* imem   = (const float*)d_in[2];
    const float* w_u    = (const float*)d_in[3];
    const float* bih_u  = (const float*)d_in[4];
    const float* bhh_u  = (const float*)d_in[5];
    const float* w_i    = (const float*)d_in[6];
    const float* bih_i  = (const float*)d_in[7];
    const float* bhh_i  = (const float*)d_in[8];
    float* out = (float*)d_out;

    limnet_compute<<<BATCH / G, 256, 0, stream>>>(
        inputs, umem, imem, w_u, bih_u, bhh_u, w_i, bih_i, bhh_i, out);

    const long OUTSEC = (long)BATCH * OUTROW;       // 264192
    const long MEMSZ  = (long)BATCH * NU * EDIM;    // 131072000

    dim3 cgrid(BATCH * CHUNKS, 2);
    limnet_copy<<<cgrid, 256, 0, stream>>>(
        umem, imem, inputs, out, out + OUTSEC, out + OUTSEC + MEMSZ);
}